// Round 7
// baseline (863.528 us; speedup 1.0000x reference)
//
#include <hip/hip_runtime.h>
#include <hip/hip_bf16.h>
#include <math.h>
#include <stdint.h>

typedef __attribute__((ext_vector_type(8))) short bf16x8;
typedef __attribute__((ext_vector_type(4))) float f32x4;
typedef __attribute__((ext_vector_type(16))) float f32x16;

#if defined(__has_builtin)
#if __has_builtin(__builtin_amdgcn_cvt_pk_bf16_f32)
#define HAVE_PK_BF16 1
#endif
#endif

// --- helpers -------------------------------------------------------------

__device__ __forceinline__ short f2bf(float f) {
    __hip_bfloat16 b = __float2bfloat16(f);
    return *reinterpret_cast<short*>(&b);
}

__device__ __forceinline__ unsigned bfbits(float f) {
    unsigned u = __float_as_uint(f);
    return (u + 0x7fffu + ((u >> 16) & 1u)) >> 16;
}

__device__ __forceinline__ unsigned pk2(float a, float b) {
#ifdef HAVE_PK_BF16
    typedef __attribute__((ext_vector_type(2))) __bf16 bf16v2;
    bf16v2 v = __builtin_amdgcn_cvt_pk_bf16_f32(a, b);
    unsigned u; __builtin_memcpy(&u, &v, 4);
    return u;
#else
    return bfbits(a) | (bfbits(b) << 16);
#endif
}

__device__ __forceinline__ float sigm(float z) { return 1.0f / (1.0f + __expf(-z)); }
__device__ __forceinline__ float silu(float z) { return z * sigm(z); }
__device__ __forceinline__ float tanh_fast(float x) {
    float e = __expf(2.0f * x);
    return 1.0f - 2.0f / (e + 1.0f);
}

// --- CSR build ----------------------------------------------------------

__global__ void hist_kernel(const int* __restrict__ edst, int* __restrict__ counts, int E) {
    int e = blockIdx.x * blockDim.x + threadIdx.x;
    if (e < E) atomicAdd(&counts[edst[e]], 1);
}

__global__ __launch_bounds__(1024)
void scan1_kernel(const int* __restrict__ counts, int* __restrict__ local,
                  int* __restrict__ bsum, int N) {
    __shared__ int sW[16];
    const int tid = threadIdx.x, lane = tid & 63, wv = tid >> 6;
    int i = blockIdx.x * 1024 + tid;
    int v = (i < N) ? counts[i] : 0;
    int s = v;
    #pragma unroll
    for (int d = 1; d < 64; d <<= 1) {
        int t = __shfl_up(s, d, 64);
        if (lane >= d) s += t;
    }
    if (lane == 63) sW[wv] = s;
    __syncthreads();
    if (wv == 0) {
        int w = (lane < 16) ? sW[lane] : 0;
        #pragma unroll
        for (int d = 1; d < 16; d <<= 1) {
            int t = __shfl_up(w, d, 64);
            if (lane >= d) w += t;
        }
        if (lane < 16) sW[lane] = w;
    }
    __syncthreads();
    int waveoff = (wv == 0) ? 0 : sW[wv - 1];
    if (i < N) local[i] = waveoff + s - v;
    if (tid == 0) bsum[blockIdx.x] = sW[15];
}

__global__ __launch_bounds__(1024)
void scan2_kernel(int* __restrict__ bsum, int nb) {
    __shared__ int sW[16];
    const int tid = threadIdx.x, lane = tid & 63, wv = tid >> 6;
    int v = (tid < nb) ? bsum[tid] : 0;
    int s = v;
    #pragma unroll
    for (int d = 1; d < 64; d <<= 1) {
        int t = __shfl_up(s, d, 64);
        if (lane >= d) s += t;
    }
    if (lane == 63) sW[wv] = s;
    __syncthreads();
    if (wv == 0) {
        int w = (lane < 16) ? sW[lane] : 0;
        #pragma unroll
        for (int d = 1; d < 16; d <<= 1) {
            int t = __shfl_up(w, d, 64);
            if (lane >= d) w += t;
        }
        if (lane < 16) sW[lane] = w;
    }
    __syncthreads();
    int waveoff = (wv == 0) ? 0 : sW[wv - 1];
    if (tid < nb) bsum[tid] = waveoff + s - v;
}

__global__ void scan3_kernel(const int* __restrict__ local, const int* __restrict__ bsum,
                             int* __restrict__ off, int* __restrict__ cursor,
                             int N, int E) {
    int i = blockIdx.x * blockDim.x + threadIdx.x;
    if (i < N) {
        int v = local[i] + bsum[i >> 10];
        off[i] = v;
        cursor[i] = v;
    }
    if (i == 0) off[N] = E;
}

__global__ void scatter_kernel(const int* __restrict__ edst,
                               int* __restrict__ cursor, int* __restrict__ eslot, int E) {
    int e = blockIdx.x * blockDim.x + threadIdx.x;
    if (e < E) {
        int d = edst[e];
        int p = atomicAdd(&cursor[d], 1);
        eslot[e] = p;
    }
}

// --- prestage ------------------------------------------------------------

__global__ void h2bf_kernel(const float* __restrict__ h, short* __restrict__ hb, int n) {
    int i = blockIdx.x * blockDim.x + threadIdx.x;
    if (i < n) hb[i] = f2bf(h[i]);
}

// weights -> MFMA A-fragment order (bf16).
// Edge mats in 32x32x16 layout WITH bias folded as an extra K-chunk:
//   A[m=32T+(L&31)][k=16C+8p+j], p=L>>5; k<K -> W[k*64+f]; k==K -> bias[f]; else 0
//   Wm1: 13 C x 2 T = 26 frags [0,26) | Wm2: 5x2=10 [26,36) | Wx1: 10 [36,46)
//   piece index = frag*64 + L, 2944 pieces total.
// Node mats in 16x16x32 layout (unchanged): Wh1 1024 pieces, Wh2 512, base 2944.
__global__ void wfrag_kernel(const float* __restrict__ Wm1, const float* __restrict__ Wm2,
                             const float* __restrict__ Wx1, const float* __restrict__ Wh1,
                             const float* __restrict__ Wh2,
                             const float* __restrict__ bm1, const float* __restrict__ bm2,
                             const float* __restrict__ bx1, const float* __restrict__ stds,
                             short* __restrict__ out, float* __restrict__ istd_out) {
    int P = blockIdx.x * blockDim.x + threadIdx.x;
    if (P < 64) istd_out[P] = 1.0f / stds[P];
    if (P >= 4480) return;
    short tmp[8] __attribute__((aligned(16)));
    if (P < 2944) {
        int frag = P >> 6, L = P & 63;
        int p = L >> 5, m32 = L & 31;
        const float* W; const float* bias; int K;
        if (frag < 26)      { W = Wm1; bias = bm1; K = 192; }
        else if (frag < 36) { W = Wm2; bias = bm2; K = 64; frag -= 26; }
        else                { W = Wx1; bias = bx1; K = 64; frag -= 36; }
        int C = frag >> 1, T = frag & 1;
        int f = 32 * T + m32;
        #pragma unroll
        for (int j = 0; j < 8; ++j) {
            int k = 16 * C + 8 * p + j;
            float v = (k < K) ? W[k * 64 + f] : ((k == K) ? bias[f] : 0.0f);
            tmp[j] = f2bf(v);
        }
    } else {
        int Q = P - 2944;
        const float* W; int fi;
        if (Q < 1024) { W = Wh1; fi = Q; } else { W = Wh2; fi = Q - 1024; }
        int c = fi >> 8, t = (fi >> 6) & 3, L = fi & 63;
        int m = L & 15, qq = L >> 4;
        #pragma unroll
        for (int j = 0; j < 8; ++j) {
            int k = c * 32 + qq * 8 + j;
            tmp[j] = f2bf(W[k * 64 + t * 16 + m]);
        }
    }
    *(bf16x8*)&out[P * 8] = *(const bf16x8*)tmp;
}

// --- edge kernel v2: barrier-free waves, 32x32x16 MFMA ------------------
// 512 thr = 8 independent waves; each wave owns 32 edges/group (grid-stride).
// B-frags: h from direct global 16-B gathers, rbf computed in-lane,
// bias chunk = constant. LDS: weights 47104 B (shared RO) + per-wave
// 32x64-short slice (m1/m overlay, XOR-swizzled) 32768 B = 79872 B -> 2 blk/CU.

__global__ __launch_bounds__(512, 4)
void edge_kernel(const short* __restrict__ hbf, const float* __restrict__ x,
                 const int* __restrict__ edst, const int* __restrict__ esrc,
                 const int* __restrict__ eslot,
                 const float* __restrict__ means, const float* __restrict__ istd_g,
                 const short* __restrict__ wfrag,
                 const float* __restrict__ Wa, const float* __restrict__ ba,
                 const float* __restrict__ Wx2,
                 short* __restrict__ msg, float4* __restrict__ disp,
                 int E, int ngroups)
{
    __shared__ short sWf[46 * 512];      // 47104 B
    __shared__ short sI[8 * 32 * 64];    // 32768 B

    const int tid  = threadIdx.x;
    const int lane = tid & 63;
    const int wv   = tid >> 6;
    const int p    = lane >> 5;          // 0..1 (k-half)
    const int e    = lane & 31;          // edge within group
    const int sw   = e & 7;

    {
        const bf16x8* s8 = (const bf16x8*)wfrag;
        bf16x8* d8 = (bf16x8*)sWf;
        #pragma unroll
        for (int i = 0; i < 6; ++i) {
            int idx = tid + i * 512;
            if (idx < 2944) d8[idx] = s8[idx];
        }
    }
    __syncthreads();                     // once, before the loop

    const bf16x8* sWfA = (const bf16x8*)sWf;
    short* myI = &sI[(wv * 32 + e) * 64];
    const bf16x8* hb8 = (const bf16x8*)hbf;

    bf16x8 bOne = {0,0,0,0,0,0,0,0};
    if (p == 0) bOne[0] = (short)0x3F80;  // bf16 1.0 at k==K

    const float ba_s = ba[0];

    int gw = blockIdx.x * 8 + wv;
    const int gstride = gridDim.x * 8;
    if (gw >= ngroups) return;

    // idx prefetch (1-deep)
    int ed, es, slot;
    {
        int eg = gw * 32 + e; if (eg >= E) eg = E - 1;
        ed = edst[eg]; es = esrc[eg]; slot = eslot[eg];
    }

    for (int g = gw; g < ngroups; g += gstride) {
        const bool validE = (g * 32 + e) < E;
        const int edc = ed, esc = es, slotc = slot;

        // ---- issue gathers for this group ----
        bf16x8 hd[4], hs[4];
        #pragma unroll
        for (int c = 0; c < 4; ++c) {
            hd[c] = hb8[(size_t)edc * 8 + 2 * c + p];
            hs[c] = hb8[(size_t)esc * 8 + 2 * c + p];
        }
        float xd0 = x[edc * 3 + 0], xd1 = x[edc * 3 + 1], xd2 = x[edc * 3 + 2];
        float xs0 = x[esc * 3 + 0], xs1 = x[esc * 3 + 1], xs2 = x[esc * 3 + 2];

        // ---- prefetch next group's indices ----
        {
            int gn = g + gstride; if (gn >= ngroups) gn = g;
            int eg = gn * 32 + e; if (eg >= E) eg = E - 1;
            ed = edst[eg]; es = esrc[eg]; slot = eslot[eg];
        }

        // ---- geometry ----
        float dx = xd0 - xs0, dy = xd1 - xs1, dz = xd2 - xs2;
        float dist = sqrtf(dx * dx + dy * dy + dz * dz);
        float inv = 1.0f / dist;
        float mskE = (validE && dist <= 3.0f) ? 1.0f : 0.0f;

        // ---- rbf frags (computed in-lane) ----
        bf16x8 rbf[4];
        #pragma unroll
        for (int cc = 0; cc < 4; ++cc) {
            int gb = 16 * cc + 8 * p;
            f32x4 m0 = *(const f32x4*)&means[gb];
            f32x4 m1 = *(const f32x4*)&means[gb + 4];
            f32x4 i0 = *(const f32x4*)&istd_g[gb];
            f32x4 i1 = *(const f32x4*)&istd_g[gb + 4];
            float ev[8];
            #pragma unroll
            for (int j = 0; j < 4; ++j) {
                float t0 = (dist - m0[j]) * i0[j];
                float t1 = (dist - m1[j]) * i1[j];
                ev[j]     = __expf(-0.5f * t0 * t0);
                ev[4 + j] = __expf(-0.5f * t1 * t1);
            }
            unsigned tu[4] __attribute__((aligned(16)));
            tu[0] = pk2(ev[0], ev[1]); tu[1] = pk2(ev[2], ev[3]);
            tu[2] = pk2(ev[4], ev[5]); tu[3] = pk2(ev[6], ev[7]);
            rbf[cc] = *(const bf16x8*)tu;
        }

        // ---- GEMM1: [32,192+bias]@[.,64] -> acc (bias folded) ----
        f32x16 acc0 = {}, acc1 = {};
        #pragma unroll
        for (int c = 0; c < 4; ++c) {
            acc0 = __builtin_amdgcn_mfma_f32_32x32x16_bf16(sWfA[(2*c+0)*64 + lane], hd[c], acc0, 0,0,0);
            acc1 = __builtin_amdgcn_mfma_f32_32x32x16_bf16(sWfA[(2*c+1)*64 + lane], hd[c], acc1, 0,0,0);
        }
        #pragma unroll
        for (int c = 0; c < 4; ++c) {
            acc0 = __builtin_amdgcn_mfma_f32_32x32x16_bf16(sWfA[(8+2*c)*64 + lane], hs[c], acc0, 0,0,0);
            acc1 = __builtin_amdgcn_mfma_f32_32x32x16_bf16(sWfA[(9+2*c)*64 + lane], hs[c], acc1, 0,0,0);
        }
        #pragma unroll
        for (int c = 0; c < 4; ++c) {
            acc0 = __builtin_amdgcn_mfma_f32_32x32x16_bf16(sWfA[(16+2*c)*64 + lane], rbf[c], acc0, 0,0,0);
            acc1 = __builtin_amdgcn_mfma_f32_32x32x16_bf16(sWfA[(17+2*c)*64 + lane], rbf[c], acc1, 0,0,0);
        }
        acc0 = __builtin_amdgcn_mfma_f32_32x32x16_bf16(sWfA[24*64 + lane], bOne, acc0, 0,0,0);
        acc1 = __builtin_amdgcn_mfma_f32_32x32x16_bf16(sWfA[25*64 + lane], bOne, acc1, 0,0,0);

        // ---- epilogue1: silu -> m1 to private LDS slice ----
        #pragma unroll
        for (int T = 0; T < 2; ++T) {
            #pragma unroll
            for (int u = 0; u < 4; ++u) {
                int up = u + 4 * T;
                float v0 = (T ? acc1[4*u+0] : acc0[4*u+0]);
                float v1 = (T ? acc1[4*u+1] : acc0[4*u+1]);
                float v2 = (T ? acc1[4*u+2] : acc0[4*u+2]);
                float v3 = (T ? acc1[4*u+3] : acc0[4*u+3]);
                uint2 st;
                st.x = pk2(silu(v0), silu(v1));
                st.y = pk2(silu(v2), silu(v3));
                *(uint2*)&myI[((up ^ sw) << 3) + 4 * p] = st;
            }
        }

        // ---- GEMM2 (+bias chunk) ----
        f32x16 g20 = {}, g21 = {};
        #pragma unroll
        for (int c = 0; c < 4; ++c) {
            bf16x8 b = *(const bf16x8*)&myI[(((2*c + p) ^ sw) << 3)];
            g20 = __builtin_amdgcn_mfma_f32_32x32x16_bf16(sWfA[(26+2*c)*64 + lane], b, g20, 0,0,0);
            g21 = __builtin_amdgcn_mfma_f32_32x32x16_bf16(sWfA[(27+2*c)*64 + lane], b, g21, 0,0,0);
        }
        g20 = __builtin_amdgcn_mfma_f32_32x32x16_bf16(sWfA[34*64 + lane], bOne, g20, 0,0,0);
        g21 = __builtin_amdgcn_mfma_f32_32x32x16_bf16(sWfA[35*64 + lane], bOne, g21, 0,0,0);

        // ---- epilogue2: silu, attention dot, scale, msg store ----
        float m2v[32];
        float patt = 0.0f;
        #pragma unroll
        for (int T = 0; T < 2; ++T) {
            #pragma unroll
            for (int u = 0; u < 4; ++u) {
                int up = u + 4 * T;
                f32x4 waq = *(const f32x4*)&Wa[8 * up + 4 * p];
                #pragma unroll
                for (int r = 0; r < 4; ++r) {
                    float v = silu(T ? g21[4*u+r] : g20[4*u+r]);
                    m2v[up * 4 + r] = v;
                    patt = fmaf(v, waq[r], patt);
                }
            }
        }
        patt += __shfl_xor(patt, 32, 64);
        const float att = sigm(patt + ba_s);
        const float sc = att * mskE;

        uint2* msgRow = (uint2*)(msg + (size_t)slotc * 64);
        #pragma unroll
        for (int up = 0; up < 8; ++up) {
            uint2 st;
            st.x = pk2(m2v[up*4+0] * sc, m2v[up*4+1] * sc);
            st.y = pk2(m2v[up*4+2] * sc, m2v[up*4+3] * sc);
            *(uint2*)&myI[((up ^ sw) << 3) + 4 * p] = st;
            if (validE) msgRow[up * 2 + p] = st;
        }

        // ---- GEMM3 (+bias chunk) ----
        f32x16 g30 = {}, g31 = {};
        #pragma unroll
        for (int c = 0; c < 4; ++c) {
            bf16x8 b = *(const bf16x8*)&myI[(((2*c + p) ^ sw) << 3)];
            g30 = __builtin_amdgcn_mfma_f32_32x32x16_bf16(sWfA[(36+2*c)*64 + lane], b, g30, 0,0,0);
            g31 = __builtin_amdgcn_mfma_f32_32x32x16_bf16(sWfA[(37+2*c)*64 + lane], b, g31, 0,0,0);
        }
        g30 = __builtin_amdgcn_mfma_f32_32x32x16_bf16(sWfA[44*64 + lane], bOne, g30, 0,0,0);
        g31 = __builtin_amdgcn_mfma_f32_32x32x16_bf16(sWfA[45*64 + lane], bOne, g31, 0,0,0);

        // ---- epilogue3: silu, Wx2 dot, tanh, disp ----
        float p3 = 0.0f;
        #pragma unroll
        for (int T = 0; T < 2; ++T) {
            #pragma unroll
            for (int u = 0; u < 4; ++u) {
                int up = u + 4 * T;
                f32x4 wxq = *(const f32x4*)&Wx2[8 * up + 4 * p];
                #pragma unroll
                for (int r = 0; r < 4; ++r)
                    p3 = fmaf(silu(T ? g31[4*u+r] : g30[4*u+r]), wxq[r], p3);
            }
        }
        p3 += __shfl_xor(p3, 32, 64);
        const float mag = tanh_fast(p3) * mskE;
        if (p == 0 && validE)
            disp[slotc] = make_float4(dx * inv * mag, dy * inv * mag, dz * inv * mag, 0.0f);
    }
}

// --- node kernel: streaming gather + MFMA MLP (unchanged from R6) -------

__global__ __launch_bounds__(256, 2)
void node_kernel(const short* __restrict__ hbf, const float* __restrict__ h,
                 const float* __restrict__ x, const int* __restrict__ off,
                 const short* __restrict__ msg, const float4* __restrict__ disp,
                 const short* __restrict__ wfragN,
                 const float* __restrict__ bh1, const float* __restrict__ bh2,
                 float* __restrict__ hout, float* __restrict__ xout, int N)
{
    __shared__ short sWfN[1536 * 8];
    __shared__ short sB[64 * 128];
    __shared__ float sOut[64 * 64];
    __shared__ float4 sXdP[64 * 4];
    __shared__ float sBiasN[2 * 64];

    const int tid  = threadIdx.x;
    const int lane = tid & 63;
    const int wv   = tid >> 6;
    const int lnE  = lane & 15;
    const int q    = lane >> 4;

    {
        const bf16x8* src8 = (const bf16x8*)wfragN;
        bf16x8* dst8 = (bf16x8*)sWfN;
        #pragma unroll
        for (int i = 0; i < 6; ++i) dst8[tid + i * 256] = src8[tid + i * 256];
        if (tid < 64) { sBiasN[tid] = bh1[tid]; sBiasN[64 + tid] = bh2[tid]; }
    }

    const int gbase = blockIdx.x * 64;
    const bf16x8* hb8 = (const bf16x8*)hbf;
    const bf16x8* sWfA = (const bf16x8*)sWfN;
    const uint2* msg_u2 = (const uint2*)msg;

    #pragma unroll
    for (int i = 0; i < 2; ++i) {
        int s = tid + i * 256;
        int row = s >> 3, sg = s & 7;
        int nc = gbase + row; if (nc >= N) nc = N - 1;
        bf16x8 v = hb8[(size_t)nc * 8 + sg];
        int phys = sg ^ (row & 7);
        *(bf16x8*)&sB[row * 128 + phys * 8] = v;
    }

    const int c = lane & 15;
    const int r = lane >> 4;
    for (int i = 0; i < 16; i += 2) {
        int rowA = wv * 16 + i, rowB = rowA + 1;
        int nA = gbase + rowA; if (nA >= N) nA = N - 1;
        int nB = gbase + rowB; if (nB >= N) nB = N - 1;
        int a0 = off[nA], a1 = off[nA + 1];
        int b0 = off[nB], b1 = off[nB + 1];
        float accA[4] = {0,0,0,0}, accB[4] = {0,0,0,0};
        int ia = a0 + r, ib = b0 + r;
        while (ia < a1 || ib < b1) {
            if (ia < a1) {
                uint2 v = msg_u2[(size_t)ia * 16 + c];
                accA[0] += __uint_as_float(v.x << 16);
                accA[1] += __uint_as_float(v.x & 0xffff0000u);
                accA[2] += __uint_as_float(v.y << 16);
                accA[3] += __uint_as_float(v.y & 0xffff0000u);
            }
            if (ib < b1) {
                uint2 v = msg_u2[(size_t)ib * 16 + c];
                accB[0] += __uint_as_float(v.x << 16);
                accB[1] += __uint_as_float(v.x & 0xffff0000u);
                accB[2] += __uint_as_float(v.y << 16);
                accB[3] += __uint_as_float(v.y & 0xffff0000u);
            }
            ia += 4; ib += 4;
        }
        #pragma unroll
        for (int j = 0; j < 4; ++j) {
            accA[j] += __shfl_xor(accA[j], 16, 64);
            accA[j] += __shfl_xor(accA[j], 32, 64);
            accB[j] += __shfl_xor(accB[j], 16, 64);
            accB[j] += __shfl_xor(accB[j], 32, 64);
        }
        if (r == 0) {
            uint2 stA, stB;
            stA.x = pk2(accA[0], accA[1]); stA.y = pk2(accA[2], accA[3]);
            stB.x = pk2(accB[0], accB[1]); stB.y = pk2(accB[2], accB[3]);
            int pA = (8 + (c >> 1)) ^ (rowA & 7);
            int pB = (8 + (c >> 1)) ^ (rowB & 7);
            *(uint2*)&sB[rowA * 128 + pA * 8 + (c & 1) * 4] = stA;
            *(uint2*)&sB[rowB * 128 + pB * 8 + (c & 1) * 4] = stB;
        }
    }

    {
        int row = tid & 63, qq = tid >> 6;
        int nc = gbase + row; if (nc >= N) nc = N - 1;
        int r0 = off[nc], r1 = off[nc + 1];
        float dx = 0.0f, dy = 0.0f, dz = 0.0f;
        for (int j = r0 + qq; j < r1; j += 4) {
            float4 d4 = disp[j];
            dx += d4.x; dy += d4.y; dz += d4.z;
        }
        sXdP[row * 4 + qq] = make_float4(dx, dy, dz, 0.0f);
    }
    __syncthreads();

    const int myrow = wv * 16 + lnE;
    const int sw = myrow & 7;
    short* bRow = &sB[myrow * 128];

    f32x4 a0 = {0,0,0,0}, a1 = {0,0,0,0}, a2 = {0,0,0,0}, a3 = {0,0,0,0};
    #pragma unroll
    for (int cc = 0; cc < 4; ++cc) {
        bf16x8 b = *(const bf16x8*)&bRow[(((cc << 2) + q) ^ sw) * 8];
        a0 = __builtin_amdgcn_mfma_f32_16x16x32_bf16(sWfA[(cc*4+0)*64 + lane], b, a0, 0,0,0);
        a1 = __builtin_amdgcn_mfma_f32_16x16x32_bf16(sWfA[(cc*4+1)*64 + lane], b, a1, 0,0,0);
        a2 = __builtin_amdgcn_mfma_f32_16x16x32_bf16(sWfA[(cc*4+2)*64 + lane], b, a2, 0,0,0);
        a3 = __builtin_amdgcn_mfma_f32_16x16x32_bf16(sWfA[(cc*4+3)*64 + lane], b, a3, 0,0,0);
    }
    {
        f32x4 a[4] = {a0, a1, a2, a3};
        #pragma unroll
        for (int t = 0; t < 4; ++t) {
            int fb = t * 16 + q * 4;
            uint2 st;
            st.x = pk2(silu(a[t][0] + sBiasN[fb + 0]), silu(a[t][1] + sBiasN[fb + 1]));
            st.y = pk2(silu(a[t][2] + sBiasN[fb + 2]), silu(a[t][3] + sBiasN[fb + 3]));
            int phys = ((t << 1) + (q >> 1)) ^ sw;
            *(uint2*)&bRow[phys * 8 + (q & 1) * 4] = st;
        }
    }
    f32x4 b0 = {0,0,0,0}, b1 = {0,0,0,0}, b2 = {0,0,0,0}, b3 = {0,0,0,0};
    #pragma unroll
    for (int cc = 0; cc < 2; ++cc) {
        bf16x8 b = *(const bf16x8*)&bRow[(((cc << 2) + q) ^ sw) * 8];
        b0 = __builtin_amdgcn_mfma_f32_16x16x32_bf16(sWfA[1024 + (cc*4+0)*64 + lane], b, b0, 0,0,0);
        b1 = __builtin_amdgcn_mfma_f32_16x16x32_bf16(sWfA[1024 + (cc*4+1)*64 + lane], b, b1, 0,0,0);
        b2 = __builtin_amdgcn_mfma_f32_16x16x32_bf16(sWfA[1024 + (cc*4+2)*64 + lane], b, b2, 0,0,0);
        b3 = __builtin_amdgcn_mfma_f32_16x16x32_bf16(sWfA[1024 + (cc*4+3)*64 + lane], b, b3, 0,0,0);
    }
    {
        f32x4 a[4] = {b0, b1, b2, b3};
        #pragma unroll
        for (int t = 0; t < 4; ++t) {
            float v4[4] __attribute__((aligned(16)));
            #pragma unroll
            for (int r2 = 0; r2 < 4; ++r2)
                v4[r2] = a[t][r2] + sBiasN[64 + t * 16 + q * 4 + r2];
            int phys = ((t << 2) + q) ^ sw;
            *(f32x4*)&sOut[myrow * 64 + phys * 4] = *(const f32x4*)v4;
        }
    }
    __syncthreads();

    #pragma unroll
    for (int i = 0; i < 16; ++i) {
        int s = tid + i * 256;
        int row = s >> 6, f = s & 63;
        int n = gbase + row;
        if (n < N) {
            int phys = ((f >> 2) ^ (row & 7)) * 4 + (f & 3);
            hout[(size_t)n * 64 + f] = h[(size_t)n * 64 + f] + sOut[row * 64 + phys];
        }
    }
    if (tid < 192) {
        int row = tid / 3, comp = tid % 3;
        int n = gbase + row;
        if (n < N) {
            float s = ((const float*)&sXdP[row * 4 + 0])[comp]
                    + ((const float*)&sXdP[row * 4 + 1])[comp]
                    + ((const float*)&sXdP[row * 4 + 2])[comp]
                    + ((const float*)&sXdP[row * 4 + 3])[comp];
            xout[(size_t)n * 3 + comp] = x[(size_t)n * 3 + comp] + s;
        }
    }
}

// --- launch --------------------------------------------------------------

extern "C" void kernel_launch(void* const* d_in, const int* in_sizes, int n_in,
                              void* d_out, int out_size, void* d_ws, size_t ws_size,
                              hipStream_t stream) {
    const float* h    = (const float*)d_in[0];
    const float* x    = (const float*)d_in[1];
    const int*   edst = (const int*)d_in[2];
    const int*   esrc = (const int*)d_in[3];
    const float* means= (const float*)d_in[4];
    const float* stds = (const float*)d_in[5];
    const float* Wm1  = (const float*)d_in[6];
    const float* bm1  = (const float*)d_in[7];
    const float* Wm2  = (const float*)d_in[8];
    const float* bm2  = (const float*)d_in[9];
    const float* Wa   = (const float*)d_in[10];
    const float* ba   = (const float*)d_in[11];
    const float* Wx1  = (const float*)d_in[12];
    const float* bx1  = (const float*)d_in[13];
    const float* Wx2  = (const float*)d_in[14];
    const float* Wh1  = (const float*)d_in[15];
    const float* bh1  = (const float*)d_in[16];
    const float* Wh2  = (const float*)d_in[17];
    const float* bh2  = (const float*)d_in[18];

    const int N = in_sizes[0] / 64;
    const int E = in_sizes[2];
    const int nb = (N + 1023) / 1024;

    float* hout = (float*)d_out;
    float* xout = hout + (size_t)N * 64;

    // workspace layout
    uintptr_t wp = (uintptr_t)d_ws;
    int* counts = (int*)wp;                 wp += (size_t)N * 4;
    int* off    = (int*)wp;                 wp += (size_t)(N + 1) * 4;
    int* cursor = (int*)wp;                 wp += (size_t)N * 4;
    int* local  = (int*)wp;                 wp += (size_t)N * 4;
    int* bsum   = (int*)wp;                 wp += 1024 * 4;
    int* eslot  = (int*)wp;                 wp += (size_t)E * 4;
    wp = (wp + 255) & ~(uintptr_t)255;
    short* msg  = (short*)wp;               wp += (size_t)E * 64 * 2;
    wp = (wp + 255) & ~(uintptr_t)255;
    float4* disp = (float4*)wp;             wp += (size_t)E * 16;
    wp = (wp + 255) & ~(uintptr_t)255;
    short* hbf  = (short*)wp;               wp += (size_t)N * 64 * 2;
    wp = (wp + 255) & ~(uintptr_t)255;
    short* wfrag = (short*)wp;              wp += 4480 * 8 * 2;
    wp = (wp + 255) & ~(uintptr_t)255;
    float* istd_g = (float*)wp;             wp += 64 * 4;

    // CSR offsets + per-edge slots
    hipMemsetAsync(counts, 0, (size_t)N * 4, stream);
    hist_kernel<<<(E + 255) / 256, 256, 0, stream>>>(edst, counts, E);
    scan1_kernel<<<nb, 1024, 0, stream>>>(counts, local, bsum, N);
    scan2_kernel<<<1, 1024, 0, stream>>>(bsum, nb);
    scan3_kernel<<<(N + 255) / 256, 256, 0, stream>>>(local, bsum, off, cursor, N, E);
    scatter_kernel<<<(E + 255) / 256, 256, 0, stream>>>(edst, cursor, eslot, E);

    // prestage
    h2bf_kernel<<<(N * 64 + 255) / 256, 256, 0, stream>>>(h, hbf, N * 64);
    wfrag_kernel<<<18, 256, 0, stream>>>(Wm1, Wm2, Wx1, Wh1, Wh2,
                                         bm1, bm2, bx1, stds, wfrag, istd_g);

    // edge pipeline
    const int ngroups = (E + 31) / 32;
    edge_kernel<<<512, 512, 0, stream>>>(hbf, x, edst, esrc, eslot, means, istd_g,
                                         wfrag, Wa, ba, Wx2, msg, disp, E, ngroups);

    // node update
    node_kernel<<<(N + 63) / 64, 256, 0, stream>>>(hbf, h, x, off, msg, disp,
                                                   wfrag + 2944 * 8,
                                                   bh1, bh2, hout, xout, N);
}

// Round 8
// 368.518 us; speedup vs baseline: 2.3432x; 2.3432x over previous
//
#include <hip/hip_runtime.h>
#include <hip/hip_bf16.h>
#include <math.h>
#include <stdint.h>

typedef __attribute__((ext_vector_type(8))) short bf16x8;
typedef __attribute__((ext_vector_type(4))) float f32x4;

#if defined(__has_builtin)
#if __has_builtin(__builtin_amdgcn_cvt_pk_bf16_f32)
#define HAVE_PK_BF16 1
#endif
#if __has_builtin(__builtin_amdgcn_rcpf)
#define HAVE_RCP 1
#endif
#if __has_builtin(__builtin_amdgcn_exp2f)
#define HAVE_EXP2 1
#endif
#endif

// --- helpers -------------------------------------------------------------

__device__ __forceinline__ short f2bf(float f) {
    __hip_bfloat16 b = __float2bfloat16(f);
    return *reinterpret_cast<short*>(&b);
}

__device__ __forceinline__ unsigned bfbits(float f) {
    unsigned u = __float_as_uint(f);
    return (u + 0x7fffu + ((u >> 16) & 1u)) >> 16;
}

__device__ __forceinline__ unsigned pk2(float a, float b) {
#ifdef HAVE_PK_BF16
    typedef __attribute__((ext_vector_type(2))) __bf16 bf16v2;
    bf16v2 v = __builtin_amdgcn_cvt_pk_bf16_f32(a, b);
    unsigned u; __builtin_memcpy(&u, &v, 4);
    return u;
#else
    return bfbits(a) | (bfbits(b) << 16);
#endif
}

__device__ __forceinline__ float frcp(float x) {
#ifdef HAVE_RCP
    return __builtin_amdgcn_rcpf(x);     // v_rcp_f32, 1 inst
#else
    return 1.0f / x;
#endif
}

__device__ __forceinline__ float fexp2(float x) {
#ifdef HAVE_EXP2
    return __builtin_amdgcn_exp2f(x);    // v_exp_f32, 1 inst
#else
    return __expf(x * 0.6931471806f);
#endif
}

#define LOG2E 1.44269504f

__device__ __forceinline__ float sigm(float z) {
    return frcp(1.0f + fexp2(-LOG2E * z));
}
__device__ __forceinline__ float silu(float z) { return z * sigm(z); }
__device__ __forceinline__ float tanh_fast(float x) {
    return 1.0f - 2.0f * frcp(1.0f + fexp2(2.0f * LOG2E * x));
}

// --- CSR build ----------------------------------------------------------

__global__ void hist_kernel(const int* __restrict__ edst, int* __restrict__ counts, int E) {
    int e = blockIdx.x * blockDim.x + threadIdx.x;
    if (e < E) atomicAdd(&counts[edst[e]], 1);
}

__global__ __launch_bounds__(1024)
void scan1_kernel(const int* __restrict__ counts, int* __restrict__ local,
                  int* __restrict__ bsum, int N) {
    __shared__ int sW[16];
    const int tid = threadIdx.x, lane = tid & 63, wv = tid >> 6;
    int i = blockIdx.x * 1024 + tid;
    int v = (i < N) ? counts[i] : 0;
    int s = v;
    #pragma unroll
    for (int d = 1; d < 64; d <<= 1) {
        int t = __shfl_up(s, d, 64);
        if (lane >= d) s += t;
    }
    if (lane == 63) sW[wv] = s;
    __syncthreads();
    if (wv == 0) {
        int w = (lane < 16) ? sW[lane] : 0;
        #pragma unroll
        for (int d = 1; d < 16; d <<= 1) {
            int t = __shfl_up(w, d, 64);
            if (lane >= d) w += t;
        }
        if (lane < 16) sW[lane] = w;
    }
    __syncthreads();
    int waveoff = (wv == 0) ? 0 : sW[wv - 1];
    if (i < N) local[i] = waveoff + s - v;
    if (tid == 0) bsum[blockIdx.x] = sW[15];
}

__global__ __launch_bounds__(1024)
void scan2_kernel(int* __restrict__ bsum, int nb) {
    __shared__ int sW[16];
    const int tid = threadIdx.x, lane = tid & 63, wv = tid >> 6;
    int v = (tid < nb) ? bsum[tid] : 0;
    int s = v;
    #pragma unroll
    for (int d = 1; d < 64; d <<= 1) {
        int t = __shfl_up(s, d, 64);
        if (lane >= d) s += t;
    }
    if (lane == 63) sW[wv] = s;
    __syncthreads();
    if (wv == 0) {
        int w = (lane < 16) ? sW[lane] : 0;
        #pragma unroll
        for (int d = 1; d < 16; d <<= 1) {
            int t = __shfl_up(w, d, 64);
            if (lane >= d) w += t;
        }
        if (lane < 16) sW[lane] = w;
    }
    __syncthreads();
    int waveoff = (wv == 0) ? 0 : sW[wv - 1];
    if (tid < nb) bsum[tid] = waveoff + s - v;
}

__global__ void scan3_kernel(const int* __restrict__ local, const int* __restrict__ bsum,
                             int* __restrict__ off, int* __restrict__ cursor,
                             int N, int E) {
    int i = blockIdx.x * blockDim.x + threadIdx.x;
    if (i < N) {
        int v = local[i] + bsum[i >> 10];
        off[i] = v;
        cursor[i] = v;
    }
    if (i == 0) off[N] = E;
}

__global__ void scatter_kernel(const int* __restrict__ edst,
                               int* __restrict__ cursor, int* __restrict__ eslot, int E) {
    int e = blockIdx.x * blockDim.x + threadIdx.x;
    if (e < E) {
        int d = edst[e];
        int p = atomicAdd(&cursor[d], 1);
        eslot[e] = p;
    }
}

// --- prestage ------------------------------------------------------------

__global__ void h2bf_kernel(const float* __restrict__ h, short* __restrict__ hb, int n) {
    int i = blockIdx.x * blockDim.x + threadIdx.x;
    if (i < n) hb[i] = f2bf(h[i]);
}

// weights -> MFMA A-fragment order (bf16)
// layout: Wm1 [0,1536) | Wm2 [1536,2048) | Wx1 [2048,2560) | Wh1 [2560,3584) | Wh2 [3584,4096)
__global__ void wfrag_kernel(const float* __restrict__ Wm1, const float* __restrict__ Wm2,
                             const float* __restrict__ Wx1, const float* __restrict__ Wh1,
                             const float* __restrict__ Wh2, short* __restrict__ out) {
    int F = blockIdx.x * blockDim.x + threadIdx.x;
    if (F >= 4096) return;
    const float* W; int fi;
    if (F < 1536)      { W = Wm1; fi = F; }
    else if (F < 2048) { W = Wm2; fi = F - 1536; }
    else if (F < 2560) { W = Wx1; fi = F - 2048; }
    else if (F < 3584) { W = Wh1; fi = F - 2560; }
    else               { W = Wh2; fi = F - 3584; }
    int c = fi >> 8;
    int t = (fi >> 6) & 3;
    int L = fi & 63;
    int m = L & 15, qq = L >> 4;
    short tmp[8] __attribute__((aligned(16)));
    #pragma unroll
    for (int j = 0; j < 8; ++j) {
        int k = c * 32 + qq * 8 + j;
        tmp[j] = f2bf(W[k * 64 + t * 16 + m]);
    }
    *(bf16x8*)&out[F * 8] = *(const bf16x8*)tmp;
}

// --- edge kernel: R6 structure + fast math + register constants ---------

__global__ __launch_bounds__(256, 2)
void edge_kernel(const short* __restrict__ hbf, const float* __restrict__ x,
                 const int* __restrict__ edst, const int* __restrict__ esrc,
                 const int* __restrict__ eslot,
                 const float* __restrict__ means, const float* __restrict__ stds,
                 const short* __restrict__ wfrag,
                 const float* __restrict__ bm1, const float* __restrict__ bm2,
                 const float* __restrict__ Wa, const float* __restrict__ ba,
                 const float* __restrict__ bx1, const float* __restrict__ Wx2,
                 short* __restrict__ msg, float4* __restrict__ disp,
                 int E, int ngroups)
{
    __shared__ short sWf[2560 * 8];     // 40960 B
    __shared__ short sInp[64 * 256];    // 32768 B
    __shared__ float sGeo[256];         // dirx|diry|dirz|mask
    __shared__ int   sSlot[64];
    __shared__ float sMeans[64], sIstd[64];

    const int tid  = threadIdx.x;
    const int lane = tid & 63;
    const int wv   = tid >> 6;
    const int lnE  = lane & 15;
    const int q    = lane >> 4;
    const int ebase = wv * 16;
    const int seg  = tid & 7;

    // staging row constants
    int serow[4], sblkv[4];
    bool isDst[4];
    #pragma unroll
    for (int i = 0; i < 4; ++i) {
        int s = tid + i * 256;
        int row = s >> 3;
        serow[i] = row & 63;
        sblkv[i] = ((row >> 6) * 8 + seg) ^ (serow[i] & 7);
        isDst[i] = (row < 64);
    }

    {
        const bf16x8* src8 = (const bf16x8*)wfrag;
        bf16x8* dst8 = (bf16x8*)sWf;
        #pragma unroll
        for (int i = 0; i < 10; ++i) dst8[tid + i * 256] = src8[tid + i * 256];
        if (tid < 64) {
            sMeans[tid] = means[tid];
            sIstd[tid]  = frcp(stds[tid]);
        }
    }

    // per-lane loop-invariant constants in registers (f = t*16 + q*4 + r)
    float bm1R[16], bm2R[16], bx1R[16], waR[16], wx2R[16];
    #pragma unroll
    for (int t = 0; t < 4; ++t)
        #pragma unroll
        for (int r = 0; r < 4; ++r) {
            int f = t * 16 + q * 4 + r;
            bm1R[t * 4 + r] = bm1[f];
            bm2R[t * 4 + r] = bm2[f];
            bx1R[t * 4 + r] = bx1[f];
            waR[t * 4 + r]  = Wa[f];
            wx2R[t * 4 + r] = Wx2[f];
        }
    const float ba_s = ba[0];

    const bf16x8* hb8  = (const bf16x8*)hbf;
    const bf16x8* sWfA = (const bf16x8*)sWf;
    bf16x8* msg8 = (bf16x8*)msg;
    const int gstep = gridDim.x;

    auto ldIdx = [&](int gg, int ni[4], int& dN, int& sN) {
        int gc = gg < ngroups ? gg : ngroups - 1;
        int gb = gc * 64;
        #pragma unroll
        for (int i = 0; i < 4; ++i) {
            int eg = gb + serow[i]; if (eg >= E) eg = E - 1;
            ni[i] = isDst[i] ? edst[eg] : esrc[eg];
        }
        int eg2 = gb + lane; if (eg2 >= E) eg2 = E - 1;
        dN = edst[eg2]; sN = esrc[eg2];
    };
    auto ldPay = [&](int gg, const int ni[4], int dN, int sN,
                     bf16x8 hv[4], float xd[3], float xs[3], int& slot) {
        #pragma unroll
        for (int i = 0; i < 4; ++i) hv[i] = hb8[(size_t)ni[i] * 8 + seg];
        xd[0] = x[dN * 3 + 0]; xd[1] = x[dN * 3 + 1]; xd[2] = x[dN * 3 + 2];
        xs[0] = x[sN * 3 + 0]; xs[1] = x[sN * 3 + 1]; xs[2] = x[sN * 3 + 2];
        int gc = gg < ngroups ? gg : ngroups - 1;
        int eg2 = gc * 64 + lane; if (eg2 >= E) eg2 = E - 1;
        slot = eslot[eg2];
    };

    int g = blockIdx.x;
    if (g >= ngroups) return;

    int niA[4], dA, sA, slotA;
    bf16x8 hvA[4];
    float xdA[3], xsA[3];
    int niB[4], dB, sB2;
    ldIdx(g, niA, dA, sA);
    ldPay(g, niA, dA, sA, hvA, xdA, xsA, slotA);
    ldIdx(g + gstep, niB, dB, sB2);

    for (; g < ngroups; g += gstep) {
        const int gbase = g * 64;
        __syncthreads();   // LDS free (prev group's stores done)

        // ---- stage group g from registers ----
        #pragma unroll
        for (int i = 0; i < 4; ++i)
            *(bf16x8*)&sInp[serow[i] * 256 + sblkv[i] * 8] = hvA[i];

        float dx = xdA[0] - xsA[0], dy = xdA[1] - xsA[1], dz = xdA[2] - xsA[2];
        float dist = sqrtf(dx * dx + dy * dy + dz * dz);
        float inv = frcp(dist);
        float msk = (dist <= 3.0f) ? 1.0f : 0.0f;
        if (tid < 64) {
            sGeo[tid] = dx * inv; sGeo[64 + tid] = dy * inv; sGeo[128 + tid] = dz * inv;
            sGeo[192 + tid] = msk;
            sSlot[tid] = slotA;
        }
        {
            float ev[16];
            #pragma unroll
            for (int j = 0; j < 16; ++j) {
                int gg2 = wv * 16 + j;
                float t = (dist - sMeans[gg2]) * sIstd[gg2];
                ev[j] = fexp2(-0.7213475f * t * t);
            }
            unsigned tu[4] __attribute__((aligned(16)));
            #pragma unroll
            for (int j2 = 0; j2 < 4; ++j2) tu[j2] = pk2(ev[2 * j2], ev[2 * j2 + 1]);
            int p0 = (16 + 2 * wv) ^ (lane & 7);
            *(bf16x8*)&sInp[lane * 256 + p0 * 8] = *(const bf16x8*)tu;
            #pragma unroll
            for (int j2 = 0; j2 < 4; ++j2) tu[j2] = pk2(ev[8 + 2 * j2], ev[9 + 2 * j2]);
            int p1 = (17 + 2 * wv) ^ (lane & 7);
            *(bf16x8*)&sInp[lane * 256 + p1 * 8] = *(const bf16x8*)tu;
        }

        // ---- prefetch next group ----
        bf16x8 hvB[4]; float xdB[3], xsB[3]; int slotB;
        ldPay(g + gstep, niB, dB, sB2, hvB, xdB, xsB, slotB);
        int niC[4], dC, sC;
        ldIdx(g + 2 * gstep, niC, dC, sC);

        __syncthreads();

        // ---- compute ----
        const int myrow = ebase + lnE;
        const int sw = myrow & 7;
        short* inpRow = &sInp[myrow * 256];

        f32x4 ac0 = {0,0,0,0}, ac1 = {0,0,0,0}, ac2 = {0,0,0,0}, ac3 = {0,0,0,0};
        #pragma unroll
        for (int c = 0; c < 6; ++c) {
            bf16x8 b = *(const bf16x8*)&inpRow[(((c << 2) + q) ^ sw) * 8];
            ac0 = __builtin_amdgcn_mfma_f32_16x16x32_bf16(sWfA[(c*4+0)*64 + lane], b, ac0, 0,0,0);
            ac1 = __builtin_amdgcn_mfma_f32_16x16x32_bf16(sWfA[(c*4+1)*64 + lane], b, ac1, 0,0,0);
            ac2 = __builtin_amdgcn_mfma_f32_16x16x32_bf16(sWfA[(c*4+2)*64 + lane], b, ac2, 0,0,0);
            ac3 = __builtin_amdgcn_mfma_f32_16x16x32_bf16(sWfA[(c*4+3)*64 + lane], b, ac3, 0,0,0);
        }
        {
            f32x4 a[4] = {ac0, ac1, ac2, ac3};
            #pragma unroll
            for (int t = 0; t < 4; ++t) {
                uint2 st;
                st.x = pk2(silu(a[t][0] + bm1R[t*4+0]), silu(a[t][1] + bm1R[t*4+1]));
                st.y = pk2(silu(a[t][2] + bm1R[t*4+2]), silu(a[t][3] + bm1R[t*4+3]));
                int phys = ((t << 1) + (q >> 1)) ^ sw;
                *(uint2*)&inpRow[phys * 8 + (q & 1) * 4] = st;
            }
        }
        f32x4 b0 = {0,0,0,0}, b1 = {0,0,0,0}, b2 = {0,0,0,0}, b3 = {0,0,0,0};
        #pragma unroll
        for (int c = 0; c < 2; ++c) {
            bf16x8 b = *(const bf16x8*)&inpRow[(((c << 2) + q) ^ sw) * 8];
            b0 = __builtin_amdgcn_mfma_f32_16x16x32_bf16(sWfA[1536 + (c*4+0)*64 + lane], b, b0, 0,0,0);
            b1 = __builtin_amdgcn_mfma_f32_16x16x32_bf16(sWfA[1536 + (c*4+1)*64 + lane], b, b1, 0,0,0);
            b2 = __builtin_amdgcn_mfma_f32_16x16x32_bf16(sWfA[1536 + (c*4+2)*64 + lane], b, b2, 0,0,0);
            b3 = __builtin_amdgcn_mfma_f32_16x16x32_bf16(sWfA[1536 + (c*4+3)*64 + lane], b, b3, 0,0,0);
        }
        float m2v[16];
        float p = 0.0f;
        {
            f32x4 a[4] = {b0, b1, b2, b3};
            #pragma unroll
            for (int t = 0; t < 4; ++t)
                #pragma unroll
                for (int r = 0; r < 4; ++r) {
                    float v = silu(a[t][r] + bm2R[t * 4 + r]);
                    m2v[t * 4 + r] = v;
                    p = fmaf(v, waR[t * 4 + r], p);
                }
        }
        p += __shfl_xor(p, 16, 64);
        p += __shfl_xor(p, 32, 64);
        const float att = sigm(p + ba_s);
        const float mskE = sGeo[192 + ebase + lnE];
        const float sc = att * mskE;
        #pragma unroll
        for (int t = 0; t < 4; ++t) {
            uint2 st;
            st.x = pk2(m2v[t * 4 + 0] * sc, m2v[t * 4 + 1] * sc);
            st.y = pk2(m2v[t * 4 + 2] * sc, m2v[t * 4 + 3] * sc);
            int phys = (8 + (t << 1) + (q >> 1)) ^ sw;
            *(uint2*)&inpRow[phys * 8 + (q & 1) * 4] = st;
        }
        f32x4 c0 = {0,0,0,0}, c1 = {0,0,0,0}, c2 = {0,0,0,0}, c3 = {0,0,0,0};
        #pragma unroll
        for (int c = 0; c < 2; ++c) {
            bf16x8 b = *(const bf16x8*)&inpRow[((8 + (c << 2) + q) ^ sw) * 8];
            c0 = __builtin_amdgcn_mfma_f32_16x16x32_bf16(sWfA[2048 + (c*4+0)*64 + lane], b, c0, 0,0,0);
            c1 = __builtin_amdgcn_mfma_f32_16x16x32_bf16(sWfA[2048 + (c*4+1)*64 + lane], b, c1, 0,0,0);
            c2 = __builtin_amdgcn_mfma_f32_16x16x32_bf16(sWfA[2048 + (c*4+2)*64 + lane], b, c2, 0,0,0);
            c3 = __builtin_amdgcn_mfma_f32_16x16x32_bf16(sWfA[2048 + (c*4+3)*64 + lane], b, c3, 0,0,0);
        }
        float p3 = 0.0f;
        {
            f32x4 a[4] = {c0, c1, c2, c3};
            #pragma unroll
            for (int t = 0; t < 4; ++t)
                #pragma unroll
                for (int r = 0; r < 4; ++r)
                    p3 = fmaf(silu(a[t][r] + bx1R[t * 4 + r]), wx2R[t * 4 + r], p3);
        }
        p3 += __shfl_xor(p3, 16, 64);
        p3 += __shfl_xor(p3, 32, 64);
        const float mag = tanh_fast(p3) * mskE;
        if (q == 0) {
            int eg = gbase + ebase + lnE;
            if (eg < E) {
                int ei = ebase + lnE;
                int slot = sSlot[ei];
                disp[slot] = make_float4(sGeo[ei] * mag, sGeo[64 + ei] * mag,
                                         sGeo[128 + ei] * mag, 0.0f);
            }
        }
        // ---- per-wave msg store ----
        #pragma unroll
        for (int i = 0; i < 2; ++i) {
            int rowL = (lane >> 3) + 8 * i;
            int e = ebase + rowL;
            int off = lane & 7;
            int eg = gbase + e;
            if (eg < E) {
                int phys = (8 + off) ^ (e & 7);
                msg8[(size_t)sSlot[e] * 8 + off] = *(const bf16x8*)&sInp[e * 256 + phys * 8];
            }
        }
        // ---- rotate pipeline registers ----
        #pragma unroll
        for (int i = 0; i < 4; ++i) { hvA[i] = hvB[i]; niB[i] = niC[i]; }
        xdA[0] = xdB[0]; xdA[1] = xdB[1]; xdA[2] = xdB[2];
        xsA[0] = xsB[0]; xsA[1] = xsB[1]; xsA[2] = xsB[2];
        slotA = slotB; dB = dC; sB2 = sC;
    }
}

// --- node kernel: streaming gather + MFMA MLP ---------------------------

__global__ __launch_bounds__(256, 2)
void node_kernel(const short* __restrict__ hbf, const float* __restrict__ h,
                 const float* __restrict__ x, const int* __restrict__ off,
                 const short* __restrict__ msg, const float4* __restrict__ disp,
                 const short* __restrict__ wfragN,
                 const float* __restrict__ bh1, const float* __restrict__ bh2,
                 float* __restrict__ hout, float* __restrict__ xout, int N)
{
    __shared__ short sWfN[1536 * 8];
    __shared__ short sB[64 * 128];
    __shared__ float sOut[64 * 64];
    __shared__ float4 sXdP[64 * 4];
    __shared__ float sBiasN[2 * 64];

    const int tid  = threadIdx.x;
    const int lane = tid & 63;
    const int wv   = tid >> 6;
    const int lnE  = lane & 15;
    const int q    = lane >> 4;

    {
        const bf16x8* src8 = (const bf16x8*)wfragN;
        bf16x8* dst8 = (bf16x8*)sWfN;
        #pragma unroll
        for (int i = 0; i < 6; ++i) dst8[tid + i * 256] = src8[tid + i * 256];
        if (tid < 64) { sBiasN[tid] = bh1[tid]; sBiasN[64 + tid] = bh2[tid]; }
    }

    const int gbase = blockIdx.x * 64;
    const bf16x8* hb8 = (const bf16x8*)hbf;
    const bf16x8* sWfA = (const bf16x8*)sWfN;
    const uint2* msg_u2 = (const uint2*)msg;

    #pragma unroll
    for (int i = 0; i < 2; ++i) {
        int s = tid + i * 256;
        int row = s >> 3, sg = s & 7;
        int nc = gbase + row; if (nc >= N) nc = N - 1;
        bf16x8 v = hb8[(size_t)nc * 8 + sg];
        int phys = sg ^ (row & 7);
        *(bf16x8*)&sB[row * 128 + phys * 8] = v;
    }

    const int c = lane & 15;
    const int r = lane >> 4;
    for (int i = 0; i < 16; i += 2) {
        int rowA = wv * 16 + i, rowB = rowA + 1;
        int nA = gbase + rowA; if (nA >= N) nA = N - 1;
        int nB = gbase + rowB; if (nB >= N) nB = N - 1;
        int a0 = off[nA], a1 = off[nA + 1];
        int b0 = off[nB], b1 = off[nB + 1];
        float accA[4] = {0,0,0,0}, accB[4] = {0,0,0,0};
        int ia = a0 + r, ib = b0 + r;
        while (ia < a1 || ib < b1) {
            if (ia < a1) {
                uint2 v = msg_u2[(size_t)ia * 16 + c];
                accA[0] += __uint_as_float(v.x << 16);
                accA[1] += __uint_as_float(v.x & 0xffff0000u);
                accA[2] += __uint_as_float(v.y << 16);
                accA[3] += __uint_as_float(v.y & 0xffff0000u);
            }
            if (ib < b1) {
                uint2 v = msg_u2[(size_t)ib * 16 + c];
                accB[0] += __uint_as_float(v.x << 16);
                accB[1] += __uint_as_float(v.x & 0xffff0000u);
                accB[2] += __uint_as_float(v.y << 16);
                accB[3] += __uint_as_float(v.y & 0xffff0000u);
            }
            ia += 4; ib += 4;
        }
        #pragma unroll
        for (int j = 0; j < 4; ++j) {
            accA[j] += __shfl_xor(accA[j], 16, 64);
            accA[j] += __shfl_xor(accA[j], 32, 64);
            accB[j] += __shfl_xor(accB[j], 16, 64);
            accB[j] += __shfl_xor(accB[j], 32, 64);
        }
        if (r == 0) {
            uint2 stA, stB;
            stA.x = pk2(accA[0], accA[1]); stA.y = pk2(accA[2], accA[3]);
            stB.x = pk2(accB[0], accB[1]); stB.y = pk2(accB[2], accB[3]);
            int pA = (8 + (c >> 1)) ^ (rowA & 7);
            int pB = (8 + (c >> 1)) ^ (rowB & 7);
            *(uint2*)&sB[rowA * 128 + pA * 8 + (c & 1) * 4] = stA;
            *(uint2*)&sB[rowB * 128 + pB * 8 + (c & 1) * 4] = stB;
        }
    }

    {
        int row = tid & 63, qq = tid >> 6;
        int nc = gbase + row; if (nc >= N) nc = N - 1;
        int r0 = off[nc], r1 = off[nc + 1];
        float dx = 0.0f, dy = 0.0f, dz = 0.0f;
        for (int j = r0 + qq; j < r1; j += 4) {
            float4 d4 = disp[j];
            dx += d4.x; dy += d4.y; dz += d4.z;
        }
        sXdP[row * 4 + qq] = make_float4(dx, dy, dz, 0.0f);
    }
    __syncthreads();

    const int myrow = wv * 16 + lnE;
    const int sw = myrow & 7;
    short* bRow = &sB[myrow * 128];

    f32x4 a0 = {0,0,0,0}, a1 = {0,0,0,0}, a2 = {0,0,0,0}, a3 = {0,0,0,0};
    #pragma unroll
    for (int cc = 0; cc < 4; ++cc) {
        bf16x8 b = *(const bf16x8*)&bRow[(((cc << 2) + q) ^ sw) * 8];
        a0 = __builtin_amdgcn_mfma_f32_16x16x32_bf16(sWfA[(cc*4+0)*64 + lane], b, a0, 0,0,0);
        a1 = __builtin_amdgcn_mfma_f32_16x16x32_bf16(sWfA[(cc*4+1)*64 + lane], b, a1, 0,0,0);
        a2 = __builtin_amdgcn_mfma_f32_16x16x32_bf16(sWfA[(cc*4+2)*64 + lane], b, a2, 0,0,0);
        a3 = __builtin_amdgcn_mfma_f32_16x16x32_bf16(sWfA[(cc*4+3)*64 + lane], b, a3, 0,0,0);
    }
    {
        f32x4 a[4] = {a0, a1, a2, a3};
        #pragma unroll
        for (int t = 0; t < 4; ++t) {
            int fb = t * 16 + q * 4;
            uint2 st;
            st.x = pk2(silu(a[t][0] + sBiasN[fb + 0]), silu(a[t][1] + sBiasN[fb + 1]));
            st.y = pk2(silu(a[t][2] + sBiasN[fb + 2]), silu(a[t][3] + sBiasN[fb + 3]));
            int phys = ((t << 1) + (q >> 1)) ^ sw;
            *(uint2*)&bRow[phys * 8 + (q & 1) * 4] = st;
        }
    }
    f32x4 b0 = {0,0,0,0}, b1 = {0,0,0,0}, b2 = {0,0,0,0}, b3 = {0,0,0,0};
    #pragma unroll
    for (int cc = 0; cc < 2; ++cc) {
        bf16x8 b = *(const bf16x8*)&bRow[(((cc << 2) + q) ^ sw) * 8];
        b0 = __builtin_amdgcn_mfma_f32_16x16x32_bf16(sWfA[1024 + (cc*4+0)*64 + lane], b, b0, 0,0,0);
        b1 = __builtin_amdgcn_mfma_f32_16x16x32_bf16(sWfA[1024 + (cc*4+1)*64 + lane], b, b1, 0,0,0);
        b2 = __builtin_amdgcn_mfma_f32_16x16x32_bf16(sWfA[1024 + (cc*4+2)*64 + lane], b, b2, 0,0,0);
        b3 = __builtin_amdgcn_mfma_f32_16x16x32_bf16(sWfA[1024 + (cc*4+3)*64 + lane], b, b3, 0,0,0);
    }
    {
        f32x4 a[4] = {b0, b1, b2, b3};
        #pragma unroll
        for (int t = 0; t < 4; ++t) {
            float v4[4] __attribute__((aligned(16)));
            #pragma unroll
            for (int r2 = 0; r2 < 4; ++r2)
                v4[r2] = a[t][r2] + sBiasN[64 + t * 16 + q * 4 + r2];
            int phys = ((t << 2) + q) ^ sw;
            *(f32x4*)&sOut[myrow * 64 + phys * 4] = *(const f32x4*)v4;
        }
    }
    __syncthreads();

    #pragma unroll
    for (int i = 0; i < 16; ++i) {
        int s = tid + i * 256;
        int row = s >> 6, f = s & 63;
        int n = gbase + row;
        if (n < N) {
            int phys = ((f >> 2) ^ (row & 7)) * 4 + (f & 3);
            hout[(size_t)n * 64 + f] = h[(size_t)n * 64 + f] + sOut[row * 64 + phys];
        }
    }
    if (tid < 192) {
        int row = tid / 3, comp = tid % 3;
        int n = gbase + row;
        if (n < N) {
            float s = ((const float*)&sXdP[row * 4 + 0])[comp]
                    + ((const float*)&sXdP[row * 4 + 1])[comp]
                    + ((const float*)&sXdP[row * 4 + 2])[comp]
                    + ((const float*)&sXdP[row * 4 + 3])[comp];
            xout[(size_t)n * 3 + comp] = x[(size_t)n * 3 + comp] + s;
        }
    }
}

// --- launch --------------------------------------------------------------

extern "C" void kernel_launch(void* const* d_in, const int* in_sizes, int n_in,
                              void* d_out, int out_size, void* d_ws, size_t ws_size,
                              hipStream_t stream) {
    const float* h    = (const float*)d_in[0];
    const float* x    = (const float*)d_in[1];
    const int*   edst = (const int*)d_in[2];
    const int*   esrc = (const int*)d_in[3];
    const float* means= (const float*)d_in[4];
    const float* stds = (const float*)d_in[5];
    const float* Wm1  = (const float*)d_in[6];
    const float* bm1  = (const float*)d_in[7];
    const float* Wm2  = (const float*)d_in[8];
    const float* bm2  = (const float*)d_in[9];
    const float* Wa   = (const float*)d_in[10];
    const float* ba   = (const float*)d_in[11];
    const float* Wx1  = (const float*)d_in[12];
    const float* bx1  = (const float*)d_in[13];
    const float* Wx2  = (const float*)d_in[14];
    const float* Wh1  = (const float*)d_in[15];
    const float* bh1  = (const float*)d_in[16];
    const float* Wh2  = (const float*)d_in[17];
    const float* bh2  = (const float*)d_in[18];

    const int N = in_sizes[0] / 64;
    const int E = in_sizes[2];
    const int nb = (N + 1023) / 1024;

    float* hout = (float*)d_out;
    float* xout = hout + (size_t)N * 64;

    // workspace layout
    uintptr_t wp = (uintptr_t)d_ws;
    int* counts = (int*)wp;                 wp += (size_t)N * 4;
    int* off    = (int*)wp;                 wp += (size_t)(N + 1) * 4;
    int* cursor = (int*)wp;                 wp += (size_t)N * 4;
    int* local  = (int*)wp;                 wp += (size_t)N * 4;
    int* bsum   = (int*)wp;                 wp += 1024 * 4;
    int* eslot  = (int*)wp;                 wp += (size_t)E * 4;
    wp = (wp + 255) & ~(uintptr_t)255;
    short* msg  = (short*)wp;               wp += (size_t)E * 64 * 2;
    wp = (wp + 255) & ~(uintptr_t)255;
    float4* disp = (float4*)wp;             wp += (size_t)E * 16;
    wp = (wp + 255) & ~(uintptr_t)255;
    short* hbf  = (short*)wp;               wp += (size_t)N * 64 * 2;
    wp = (wp + 255) & ~(uintptr_t)255;
    short* wfrag = (short*)wp;              wp += 4096 * 8 * 2;

    // CSR offsets + per-edge slots
    hipMemsetAsync(counts, 0, (size_t)N * 4, stream);
    hist_kernel<<<(E + 255) / 256, 256, 0, stream>>>(edst, counts, E);
    scan1_kernel<<<nb, 1024, 0, stream>>>(counts, local, bsum, N);
    scan2_kernel<<<1, 1024, 0, stream>>>(bsum, nb);
    scan3_kernel<<<(N + 255) / 256, 256, 0, stream>>>(local, bsum, off, cursor, N, E);
    scatter_kernel<<<(E + 255) / 256, 256, 0, stream>>>(edst, cursor, eslot, E);

    // prestage
    h2bf_kernel<<<(N * 64 + 255) / 256, 256, 0, stream>>>(h, hbf, N * 64);
    wfrag_kernel<<<16, 256, 0, stream>>>(Wm1, Wm2, Wx1, Wh1, Wh2, wfrag);

    // edge pipeline
    const int ngroups = (E + 63) / 64;
    edge_kernel<<<1024, 256, 0, stream>>>(hbf, x, edst, esrc, eslot, means, stds, wfrag,
                                          bm1, bm2, Wa, ba, bx1, Wx2,
                                          msg, disp, E, ngroups);

    // node update
    node_kernel<<<(N + 63) / 64, 256, 0, stream>>>(hbf, h, x, off, msg, disp,
                                                   wfrag + 2560 * 8,
                                                   bh1, bh2, hout, xout, N);
}

// Round 10
// 353.753 us; speedup vs baseline: 2.4411x; 1.0417x over previous
//
#include <hip/hip_runtime.h>
#include <hip/hip_bf16.h>
#include <math.h>
#include <stdint.h>

typedef __attribute__((ext_vector_type(8))) short bf16x8;
typedef __attribute__((ext_vector_type(4))) float f32x4;
typedef __attribute__((ext_vector_type(2))) unsigned u32x2;

#if defined(__has_builtin)
#if __has_builtin(__builtin_amdgcn_cvt_pk_bf16_f32)
#define HAVE_PK_BF16 1
#endif
#if __has_builtin(__builtin_amdgcn_rcpf)
#define HAVE_RCP 1
#endif
#if __has_builtin(__builtin_amdgcn_exp2f)
#define HAVE_EXP2 1
#endif
#endif

// --- helpers -------------------------------------------------------------

__device__ __forceinline__ short f2bf(float f) {
    __hip_bfloat16 b = __float2bfloat16(f);
    return *reinterpret_cast<short*>(&b);
}

__device__ __forceinline__ unsigned bfbits(float f) {
    unsigned u = __float_as_uint(f);
    return (u + 0x7fffu + ((u >> 16) & 1u)) >> 16;
}

__device__ __forceinline__ unsigned pk2(float a, float b) {
#ifdef HAVE_PK_BF16
    typedef __attribute__((ext_vector_type(2))) __bf16 bf16v2;
    bf16v2 v = __builtin_amdgcn_cvt_pk_bf16_f32(a, b);
    unsigned u; __builtin_memcpy(&u, &v, 4);
    return u;
#else
    return bfbits(a) | (bfbits(b) << 16);
#endif
}

__device__ __forceinline__ float frcp(float x) {
#ifdef HAVE_RCP
    return __builtin_amdgcn_rcpf(x);
#else
    return 1.0f / x;
#endif
}

__device__ __forceinline__ float fexp2(float x) {
#ifdef HAVE_EXP2
    return __builtin_amdgcn_exp2f(x);
#else
    return __expf(x * 0.6931471806f);
#endif
}

#define LOG2E 1.44269504f

__device__ __forceinline__ float sigm(float z) {
    return frcp(1.0f + fexp2(-LOG2E * z));
}
__device__ __forceinline__ float silu(float z) { return z * sigm(z); }
__device__ __forceinline__ float tanh_fast(float x) {
    return 1.0f - 2.0f * frcp(1.0f + fexp2(2.0f * LOG2E * x));
}

// --- CSR build + h->bf16 (fused; hist records per-edge rank) ------------

__global__ void hist_h2bf_kernel(const int* __restrict__ edst, int* __restrict__ counts,
                                 int* __restrict__ rankv, int E,
                                 const float4* __restrict__ h4, uint2* __restrict__ hb4,
                                 int n4) {
    int i = blockIdx.x * blockDim.x + threadIdx.x;
    if (i < E) rankv[i] = atomicAdd(&counts[edst[i]], 1);
    if (i < n4) {
        float4 v = h4[i];
        uint2 o;
        o.x = pk2(v.x, v.y);
        o.y = pk2(v.z, v.w);
        hb4[i] = o;
    }
}

__global__ __launch_bounds__(1024)
void scan1_kernel(const int* __restrict__ counts, int* __restrict__ local,
                  int* __restrict__ bsum, int N) {
    __shared__ int sW[16];
    const int tid = threadIdx.x, lane = tid & 63, wv = tid >> 6;
    int i = blockIdx.x * 1024 + tid;
    int v = (i < N) ? counts[i] : 0;
    int s = v;
    #pragma unroll
    for (int d = 1; d < 64; d <<= 1) {
        int t = __shfl_up(s, d, 64);
        if (lane >= d) s += t;
    }
    if (lane == 63) sW[wv] = s;
    __syncthreads();
    if (wv == 0) {
        int w = (lane < 16) ? sW[lane] : 0;
        #pragma unroll
        for (int d = 1; d < 16; d <<= 1) {
            int t = __shfl_up(w, d, 64);
            if (lane >= d) w += t;
        }
        if (lane < 16) sW[lane] = w;
    }
    __syncthreads();
    int waveoff = (wv == 0) ? 0 : sW[wv - 1];
    if (i < N) local[i] = waveoff + s - v;
    if (tid == 0) bsum[blockIdx.x] = sW[15];
}

__global__ __launch_bounds__(1024)
void scan2_kernel(int* __restrict__ bsum, int nb) {
    __shared__ int sW[16];
    const int tid = threadIdx.x, lane = tid & 63, wv = tid >> 6;
    int v = (tid < nb) ? bsum[tid] : 0;
    int s = v;
    #pragma unroll
    for (int d = 1; d < 64; d <<= 1) {
        int t = __shfl_up(s, d, 64);
        if (lane >= d) s += t;
    }
    if (lane == 63) sW[wv] = s;
    __syncthreads();
    if (wv == 0) {
        int w = (lane < 16) ? sW[lane] : 0;
        #pragma unroll
        for (int d = 1; d < 16; d <<= 1) {
            int t = __shfl_up(w, d, 64);
            if (lane >= d) w += t;
        }
        if (lane < 16) sW[lane] = w;
    }
    __syncthreads();
    int waveoff = (wv == 0) ? 0 : sW[wv - 1];
    if (tid < nb) bsum[tid] = waveoff + s - v;
}

__global__ void scan3_kernel(const int* __restrict__ local, const int* __restrict__ bsum,
                             int* __restrict__ off, int N, int E) {
    int i = blockIdx.x * blockDim.x + threadIdx.x;
    if (i < N) off[i] = local[i] + bsum[i >> 10];
    if (i == 0) off[N] = E;
}

// --- prestage: weights -> MFMA A-fragment order (bf16) -------------------
// layout: Wm1 [0,1536) | Wm2 [1536,2048) | Wx1 [2048,2560) | Wh1 [2560,3584) | Wh2 [3584,4096)
__global__ void wfrag_kernel(const float* __restrict__ Wm1, const float* __restrict__ Wm2,
                             const float* __restrict__ Wx1, const float* __restrict__ Wh1,
                             const float* __restrict__ Wh2, short* __restrict__ out) {
    int F = blockIdx.x * blockDim.x + threadIdx.x;
    if (F >= 4096) return;
    const float* W; int fi;
    if (F < 1536)      { W = Wm1; fi = F; }
    else if (F < 2048) { W = Wm2; fi = F - 1536; }
    else if (F < 2560) { W = Wx1; fi = F - 2048; }
    else if (F < 3584) { W = Wh1; fi = F - 2560; }
    else               { W = Wh2; fi = F - 3584; }
    int c = fi >> 8;
    int t = (fi >> 6) & 3;
    int L = fi & 63;
    int m = L & 15, qq = L >> 4;
    short tmp[8] __attribute__((aligned(16)));
    #pragma unroll
    for (int j = 0; j < 8; ++j) {
        int k = c * 32 + qq * 8 + j;
        tmp[j] = f2bf(W[k * 64 + t * 16 + m]);
    }
    *(bf16x8*)&out[F * 8] = *(const bf16x8*)tmp;
}

// --- edge kernel: R8 structure; slot = off[dst] + rank (no eslot array) -

__global__ __launch_bounds__(256, 2)
void edge_kernel(const short* __restrict__ hbf, const float* __restrict__ x,
                 const int* __restrict__ edst, const int* __restrict__ esrc,
                 const int* __restrict__ offn, const int* __restrict__ rankv,
                 const float* __restrict__ means, const float* __restrict__ stds,
                 const short* __restrict__ wfrag,
                 const float* __restrict__ bm1, const float* __restrict__ bm2,
                 const float* __restrict__ Wa, const float* __restrict__ ba,
                 const float* __restrict__ bx1, const float* __restrict__ Wx2,
                 short* __restrict__ msg, float* __restrict__ disp,
                 int E, int ngroups)
{
    __shared__ short sWf[2560 * 8];     // 40960 B
    __shared__ short sInp[64 * 256];    // 32768 B
    __shared__ float sGeo[256];         // dirx|diry|dirz|mask
    __shared__ int   sSlot[64];
    __shared__ float sMeans[64], sIstd[64];

    const int tid  = threadIdx.x;
    const int lane = tid & 63;
    const int wv   = tid >> 6;
    const int lnE  = lane & 15;
    const int q    = lane >> 4;
    const int ebase = wv * 16;
    const int seg  = tid & 7;

    int serow[4], sblkv[4];
    bool isDst[4];
    #pragma unroll
    for (int i = 0; i < 4; ++i) {
        int s = tid + i * 256;
        int row = s >> 3;
        serow[i] = row & 63;
        sblkv[i] = ((row >> 6) * 8 + seg) ^ (serow[i] & 7);
        isDst[i] = (row < 64);
    }

    {
        const bf16x8* src8 = (const bf16x8*)wfrag;
        bf16x8* dst8 = (bf16x8*)sWf;
        #pragma unroll
        for (int i = 0; i < 10; ++i) dst8[tid + i * 256] = src8[tid + i * 256];
        if (tid < 64) {
            sMeans[tid] = means[tid];
            sIstd[tid]  = frcp(stds[tid]);
        }
    }

    float bm1R[16], bm2R[16], bx1R[16], waR[16], wx2R[16];
    #pragma unroll
    for (int t = 0; t < 4; ++t)
        #pragma unroll
        for (int r = 0; r < 4; ++r) {
            int f = t * 16 + q * 4 + r;
            bm1R[t * 4 + r] = bm1[f];
            bm2R[t * 4 + r] = bm2[f];
            bx1R[t * 4 + r] = bx1[f];
            waR[t * 4 + r]  = Wa[f];
            wx2R[t * 4 + r] = Wx2[f];
        }
    const float ba_s = ba[0];

    const bf16x8* hb8  = (const bf16x8*)hbf;
    const bf16x8* sWfA = (const bf16x8*)sWf;
    bf16x8* msg8 = (bf16x8*)msg;
    const int gstep = gridDim.x;

    auto ldIdx = [&](int gg, int ni[4], int& dN, int& sN) {
        int gc = gg < ngroups ? gg : ngroups - 1;
        int gb = gc * 64;
        #pragma unroll
        for (int i = 0; i < 4; ++i) {
            int eg = gb + serow[i]; if (eg >= E) eg = E - 1;
            ni[i] = isDst[i] ? edst[eg] : esrc[eg];
        }
        int eg2 = gb + lane; if (eg2 >= E) eg2 = E - 1;
        dN = edst[eg2]; sN = esrc[eg2];
    };
    auto ldPay = [&](int gg, const int ni[4], int dN, int sN,
                     bf16x8 hv[4], float xd[3], float xs[3], int& slot) {
        #pragma unroll
        for (int i = 0; i < 4; ++i) hv[i] = hb8[(size_t)ni[i] * 8 + seg];
        xd[0] = x[dN * 3 + 0]; xd[1] = x[dN * 3 + 1]; xd[2] = x[dN * 3 + 2];
        xs[0] = x[sN * 3 + 0]; xs[1] = x[sN * 3 + 1]; xs[2] = x[sN * 3 + 2];
        int gc = gg < ngroups ? gg : ngroups - 1;
        int eg2 = gc * 64 + lane; if (eg2 >= E) eg2 = E - 1;
        slot = offn[dN] + rankv[eg2];
    };

    int g = blockIdx.x;
    if (g >= ngroups) return;

    int niA[4], dA, sA, slotA;
    bf16x8 hvA[4];
    float xdA[3], xsA[3];
    int niB[4], dB, sB2;
    ldIdx(g, niA, dA, sA);
    ldPay(g, niA, dA, sA, hvA, xdA, xsA, slotA);
    ldIdx(g + gstep, niB, dB, sB2);

    for (; g < ngroups; g += gstep) {
        const int gbase = g * 64;
        __syncthreads();

        #pragma unroll
        for (int i = 0; i < 4; ++i)
            *(bf16x8*)&sInp[serow[i] * 256 + sblkv[i] * 8] = hvA[i];

        float dx = xdA[0] - xsA[0], dy = xdA[1] - xsA[1], dz = xdA[2] - xsA[2];
        float dist = sqrtf(dx * dx + dy * dy + dz * dz);
        float inv = frcp(dist);
        float msk = (dist <= 3.0f) ? 1.0f : 0.0f;
        if (tid < 64) {
            sGeo[tid] = dx * inv; sGeo[64 + tid] = dy * inv; sGeo[128 + tid] = dz * inv;
            sGeo[192 + tid] = msk;
            sSlot[tid] = slotA;
        }
        {
            float ev[16];
            #pragma unroll
            for (int j = 0; j < 16; ++j) {
                int gg2 = wv * 16 + j;
                float t = (dist - sMeans[gg2]) * sIstd[gg2];
                ev[j] = fexp2(-0.7213475f * t * t);
            }
            unsigned tu[4] __attribute__((aligned(16)));
            #pragma unroll
            for (int j2 = 0; j2 < 4; ++j2) tu[j2] = pk2(ev[2 * j2], ev[2 * j2 + 1]);
            int p0 = (16 + 2 * wv) ^ (lane & 7);
            *(bf16x8*)&sInp[lane * 256 + p0 * 8] = *(const bf16x8*)tu;
            #pragma unroll
            for (int j2 = 0; j2 < 4; ++j2) tu[j2] = pk2(ev[8 + 2 * j2], ev[9 + 2 * j2]);
            int p1 = (17 + 2 * wv) ^ (lane & 7);
            *(bf16x8*)&sInp[lane * 256 + p1 * 8] = *(const bf16x8*)tu;
        }

        bf16x8 hvB[4]; float xdB[3], xsB[3]; int slotB;
        ldPay(g + gstep, niB, dB, sB2, hvB, xdB, xsB, slotB);
        int niC[4], dC, sC;
        ldIdx(g + 2 * gstep, niC, dC, sC);

        __syncthreads();

        const int myrow = ebase + lnE;
        const int sw = myrow & 7;
        short* inpRow = &sInp[myrow * 256];

        f32x4 ac0 = {0,0,0,0}, ac1 = {0,0,0,0}, ac2 = {0,0,0,0}, ac3 = {0,0,0,0};
        #pragma unroll
        for (int c = 0; c < 6; ++c) {
            bf16x8 b = *(const bf16x8*)&inpRow[(((c << 2) + q) ^ sw) * 8];
            ac0 = __builtin_amdgcn_mfma_f32_16x16x32_bf16(sWfA[(c*4+0)*64 + lane], b, ac0, 0,0,0);
            ac1 = __builtin_amdgcn_mfma_f32_16x16x32_bf16(sWfA[(c*4+1)*64 + lane], b, ac1, 0,0,0);
            ac2 = __builtin_amdgcn_mfma_f32_16x16x32_bf16(sWfA[(c*4+2)*64 + lane], b, ac2, 0,0,0);
            ac3 = __builtin_amdgcn_mfma_f32_16x16x32_bf16(sWfA[(c*4+3)*64 + lane], b, ac3, 0,0,0);
        }
        {
            f32x4 a[4] = {ac0, ac1, ac2, ac3};
            #pragma unroll
            for (int t = 0; t < 4; ++t) {
                uint2 st;
                st.x = pk2(silu(a[t][0] + bm1R[t*4+0]), silu(a[t][1] + bm1R[t*4+1]));
                st.y = pk2(silu(a[t][2] + bm1R[t*4+2]), silu(a[t][3] + bm1R[t*4+3]));
                int phys = ((t << 1) + (q >> 1)) ^ sw;
                *(uint2*)&inpRow[phys * 8 + (q & 1) * 4] = st;
            }
        }
        f32x4 b0 = {0,0,0,0}, b1 = {0,0,0,0}, b2 = {0,0,0,0}, b3 = {0,0,0,0};
        #pragma unroll
        for (int c = 0; c < 2; ++c) {
            bf16x8 b = *(const bf16x8*)&inpRow[(((c << 2) + q) ^ sw) * 8];
            b0 = __builtin_amdgcn_mfma_f32_16x16x32_bf16(sWfA[1536 + (c*4+0)*64 + lane], b, b0, 0,0,0);
            b1 = __builtin_amdgcn_mfma_f32_16x16x32_bf16(sWfA[1536 + (c*4+1)*64 + lane], b, b1, 0,0,0);
            b2 = __builtin_amdgcn_mfma_f32_16x16x32_bf16(sWfA[1536 + (c*4+2)*64 + lane], b, b2, 0,0,0);
            b3 = __builtin_amdgcn_mfma_f32_16x16x32_bf16(sWfA[1536 + (c*4+3)*64 + lane], b, b3, 0,0,0);
        }
        float m2v[16];
        float p = 0.0f;
        {
            f32x4 a[4] = {b0, b1, b2, b3};
            #pragma unroll
            for (int t = 0; t < 4; ++t)
                #pragma unroll
                for (int r = 0; r < 4; ++r) {
                    float v = silu(a[t][r] + bm2R[t * 4 + r]);
                    m2v[t * 4 + r] = v;
                    p = fmaf(v, waR[t * 4 + r], p);
                }
        }
        p += __shfl_xor(p, 16, 64);
        p += __shfl_xor(p, 32, 64);
        const float att = sigm(p + ba_s);
        const float mskE = sGeo[192 + ebase + lnE];
        const float sc = att * mskE;
        #pragma unroll
        for (int t = 0; t < 4; ++t) {
            uint2 st;
            st.x = pk2(m2v[t * 4 + 0] * sc, m2v[t * 4 + 1] * sc);
            st.y = pk2(m2v[t * 4 + 2] * sc, m2v[t * 4 + 3] * sc);
            int phys = (8 + (t << 1) + (q >> 1)) ^ sw;
            *(uint2*)&inpRow[phys * 8 + (q & 1) * 4] = st;
        }
        f32x4 c0 = {0,0,0,0}, c1 = {0,0,0,0}, c2 = {0,0,0,0}, c3 = {0,0,0,0};
        #pragma unroll
        for (int c = 0; c < 2; ++c) {
            bf16x8 b = *(const bf16x8*)&inpRow[((8 + (c << 2) + q) ^ sw) * 8];
            c0 = __builtin_amdgcn_mfma_f32_16x16x32_bf16(sWfA[2048 + (c*4+0)*64 + lane], b, c0, 0,0,0);
            c1 = __builtin_amdgcn_mfma_f32_16x16x32_bf16(sWfA[2048 + (c*4+1)*64 + lane], b, c1, 0,0,0);
            c2 = __builtin_amdgcn_mfma_f32_16x16x32_bf16(sWfA[2048 + (c*4+2)*64 + lane], b, c2, 0,0,0);
            c3 = __builtin_amdgcn_mfma_f32_16x16x32_bf16(sWfA[2048 + (c*4+3)*64 + lane], b, c3, 0,0,0);
        }
        float p3 = 0.0f;
        {
            f32x4 a[4] = {c0, c1, c2, c3};
            #pragma unroll
            for (int t = 0; t < 4; ++t)
                #pragma unroll
                for (int r = 0; r < 4; ++r)
                    p3 = fmaf(silu(a[t][r] + bx1R[t * 4 + r]), wx2R[t * 4 + r], p3);
        }
        p3 += __shfl_xor(p3, 16, 64);
        p3 += __shfl_xor(p3, 32, 64);
        const float mag = tanh_fast(p3) * mskE;
        if (q == 0) {
            int eg = gbase + ebase + lnE;
            if (eg < E) {
                int ei = ebase + lnE;
                int slot = sSlot[ei];
                f32x4 dv = {sGeo[ei] * mag, sGeo[64 + ei] * mag, sGeo[128 + ei] * mag, 0.0f};
                __builtin_nontemporal_store(dv, (f32x4*)&disp[(size_t)slot * 4]);
            }
        }
        #pragma unroll
        for (int i = 0; i < 2; ++i) {
            int rowL = (lane >> 3) + 8 * i;
            int e = ebase + rowL;
            int o8 = lane & 7;
            int eg = gbase + e;
            if (eg < E) {
                int phys = (8 + o8) ^ (e & 7);
                __builtin_nontemporal_store(*(const bf16x8*)&sInp[e * 256 + phys * 8],
                                            &msg8[(size_t)sSlot[e] * 8 + o8]);
            }
        }
        #pragma unroll
        for (int i = 0; i < 4; ++i) { hvA[i] = hvB[i]; niB[i] = niC[i]; }
        xdA[0] = xdB[0]; xdA[1] = xdB[1]; xdA[2] = xdB[2];
        xsA[0] = xsB[0]; xsA[1] = xsB[1]; xsA[2] = xsB[2];
        slotA = slotB; dB = dC; sB2 = sC;
    }
}

// --- node kernel: deep-queue gather (4 rows interleaved) + MFMA MLP -----
// LDS: sWfN 24576 + sB 16384 + sOutB 8192 + sXdP 4096 + sBiasN 512 = 53760 B
// -> 3 blocks/CU (12 waves/CU).

__global__ __launch_bounds__(256, 3)
void node_kernel(const short* __restrict__ hbf, const float* __restrict__ h,
                 const float* __restrict__ x, const int* __restrict__ off,
                 const short* __restrict__ msg, const float* __restrict__ disp,
                 const short* __restrict__ wfragN,
                 const float* __restrict__ bh1, const float* __restrict__ bh2,
                 float* __restrict__ hout, float* __restrict__ xout, int N)
{
    __shared__ short sWfN[1536 * 8];
    __shared__ short sB[64 * 128];
    __shared__ short sOutB[64 * 64];
    __shared__ float4 sXdP[64 * 4];
    __shared__ float sBiasN[2 * 64];

    const int tid  = threadIdx.x;
    const int lane = tid & 63;
    const int wv   = tid >> 6;
    const int lnE  = lane & 15;
    const int q    = lane >> 4;

    {
        const bf16x8* src8 = (const bf16x8*)wfragN;
        bf16x8* dst8 = (bf16x8*)sWfN;
        #pragma unroll
        for (int i = 0; i < 6; ++i) dst8[tid + i * 256] = src8[tid + i * 256];
        if (tid < 64) { sBiasN[tid] = bh1[tid]; sBiasN[64 + tid] = bh2[tid]; }
    }

    const int gbase = blockIdx.x * 64;
    const bf16x8* hb8 = (const bf16x8*)hbf;
    const bf16x8* sWfA = (const bf16x8*)sWfN;
    const u32x2* msg_u2 = (const u32x2*)msg;

    // --- stage h rows (coalesced, swizzled) ---
    #pragma unroll
    for (int i = 0; i < 2; ++i) {
        int s = tid + i * 256;
        int row = s >> 3, sg = s & 7;
        int nc = gbase + row; if (nc >= N) nc = N - 1;
        bf16x8 v = hb8[(size_t)nc * 8 + sg];
        int phys = sg ^ (row & 7);
        *(bf16x8*)&sB[row * 128 + phys * 8] = v;
    }

    // --- msg gather: 4 rows interleaved; lane = (seg c 0..15, chunk r 0..3) ---
    const int c = lane & 15;
    const int r = lane >> 4;
    for (int i = 0; i < 16; i += 4) {
        int rr1[4], ia[4];
        float acc[4][4] = {{0,0,0,0},{0,0,0,0},{0,0,0,0},{0,0,0,0}};
        #pragma unroll
        for (int k = 0; k < 4; ++k) {
            int nc = gbase + wv * 16 + i + k; if (nc >= N) nc = N - 1;
            ia[k] = off[nc] + r;
            rr1[k] = off[nc + 1];
        }
        bool more = (ia[0] < rr1[0]) | (ia[1] < rr1[1]) | (ia[2] < rr1[2]) | (ia[3] < rr1[3]);
        while (more) {
            u32x2 v[4]; bool ld[4];
            #pragma unroll
            for (int k = 0; k < 4; ++k) {
                ld[k] = ia[k] < rr1[k];
                if (ld[k]) v[k] = __builtin_nontemporal_load(&msg_u2[(size_t)ia[k] * 16 + c]);
            }
            #pragma unroll
            for (int k = 0; k < 4; ++k) {
                if (ld[k]) {
                    acc[k][0] += __uint_as_float(v[k].x << 16);
                    acc[k][1] += __uint_as_float(v[k].x & 0xffff0000u);
                    acc[k][2] += __uint_as_float(v[k].y << 16);
                    acc[k][3] += __uint_as_float(v[k].y & 0xffff0000u);
                    ia[k] += 4;
                }
            }
            more = (ia[0] < rr1[0]) | (ia[1] < rr1[1]) | (ia[2] < rr1[2]) | (ia[3] < rr1[3]);
        }
        #pragma unroll
        for (int k = 0; k < 4; ++k) {
            #pragma unroll
            for (int j = 0; j < 4; ++j) {
                acc[k][j] += __shfl_xor(acc[k][j], 16, 64);
                acc[k][j] += __shfl_xor(acc[k][j], 32, 64);
            }
            if (r == 0) {
                int row = wv * 16 + i + k;
                uint2 st;
                st.x = pk2(acc[k][0], acc[k][1]);
                st.y = pk2(acc[k][2], acc[k][3]);
                int pA = (8 + (c >> 1)) ^ (row & 7);
                *(uint2*)&sB[row * 128 + pA * 8 + (c & 1) * 4] = st;
            }
        }
    }

    // --- disp partial sums ---
    {
        int row = tid & 63, qq = tid >> 6;
        int nc = gbase + row; if (nc >= N) nc = N - 1;
        int r0 = off[nc], r1 = off[nc + 1];
        float dx = 0.0f, dy = 0.0f, dz = 0.0f;
        for (int j = r0 + qq; j < r1; j += 4) {
            const float* d4 = &disp[(size_t)j * 4];
            dx += d4[0]; dy += d4[1]; dz += d4[2];
        }
        sXdP[row * 4 + qq] = make_float4(dx, dy, dz, 0.0f);
    }
    __syncthreads();

    // --- MFMA MLP ---
    const int myrow = wv * 16 + lnE;
    const int sw = myrow & 7;
    short* bRow = &sB[myrow * 128];

    f32x4 a0 = {0,0,0,0}, a1 = {0,0,0,0}, a2 = {0,0,0,0}, a3 = {0,0,0,0};
    #pragma unroll
    for (int cc = 0; cc < 4; ++cc) {
        bf16x8 b = *(const bf16x8*)&bRow[(((cc << 2) + q) ^ sw) * 8];
        a0 = __builtin_amdgcn_mfma_f32_16x16x32_bf16(sWfA[(cc*4+0)*64 + lane], b, a0, 0,0,0);
        a1 = __builtin_amdgcn_mfma_f32_16x16x32_bf16(sWfA[(cc*4+1)*64 + lane], b, a1, 0,0,0);
        a2 = __builtin_amdgcn_mfma_f32_16x16x32_bf16(sWfA[(cc*4+2)*64 + lane], b, a2, 0,0,0);
        a3 = __builtin_amdgcn_mfma_f32_16x16x32_bf16(sWfA[(cc*4+3)*64 + lane], b, a3, 0,0,0);
    }
    {
        f32x4 a[4] = {a0, a1, a2, a3};
        #pragma unroll
        for (int t = 0; t < 4; ++t) {
            int fb = t * 16 + q * 4;
            uint2 st;
            st.x = pk2(silu(a[t][0] + sBiasN[fb + 0]), silu(a[t][1] + sBiasN[fb + 1]));
            st.y = pk2(silu(a[t][2] + sBiasN[fb + 2]), silu(a[t][3] + sBiasN[fb + 3]));
            int phys = ((t << 1) + (q >> 1)) ^ sw;
            *(uint2*)&bRow[phys * 8 + (q & 1) * 4] = st;
        }
    }
    f32x4 b0 = {0,0,0,0}, b1 = {0,0,0,0}, b2 = {0,0,0,0}, b3 = {0,0,0,0};
    #pragma unroll
    for (int cc = 0; cc < 2; ++cc) {
        bf16x8 b = *(const bf16x8*)&bRow[(((cc << 2) + q) ^ sw) * 8];
        b0 = __builtin_amdgcn_mfma_f32_16x16x32_bf16(sWfA[1024 + (cc*4+0)*64 + lane], b, b0, 0,0,0);
        b1 = __builtin_amdgcn_mfma_f32_16x16x32_bf16(sWfA[1024 + (cc*4+1)*64 + lane], b, b1, 0,0,0);
        b2 = __builtin_amdgcn_mfma_f32_16x16x32_bf16(sWfA[1024 + (cc*4+2)*64 + lane], b, b2, 0,0,0);
        b3 = __builtin_amdgcn_mfma_f32_16x16x32_bf16(sWfA[1024 + (cc*4+3)*64 + lane], b, b3, 0,0,0);
    }
    {
        f32x4 a[4] = {b0, b1, b2, b3};
        #pragma unroll
        for (int t = 0; t < 4; ++t) {
            uint2 st;
            st.x = pk2(a[t][0] + sBiasN[64 + t * 16 + q * 4 + 0],
                       a[t][1] + sBiasN[64 + t * 16 + q * 4 + 1]);
            st.y = pk2(a[t][2] + sBiasN[64 + t * 16 + q * 4 + 2],
                       a[t][3] + sBiasN[64 + t * 16 + q * 4 + 3]);
            int phys = ((t << 1) + (q >> 1)) ^ sw;
            *(uint2*)&sOutB[myrow * 64 + phys * 8 + (q & 1) * 4] = st;
        }
    }
    __syncthreads();

    // --- coalesced stores (read bf16 delta, add h in fp32) ---
    #pragma unroll
    for (int i = 0; i < 8; ++i) {
        int s = tid + i * 256;          // 0..2047; 32 uints per row
        int row = s >> 5, u = s & 31;
        int n = gbase + row;
        if (n < N) {
            int blk = u >> 2;
            int phys = blk ^ (row & 7);
            unsigned pv = *(const unsigned*)&sOutB[row * 64 + phys * 8 + (u & 3) * 2];
            int f = u * 2;
            float2 hv = *(const float2*)&h[(size_t)n * 64 + f];
            float2 o;
            o.x = hv.x + __uint_as_float(pv << 16);
            o.y = hv.y + __uint_as_float(pv & 0xffff0000u);
            *(float2*)&hout[(size_t)n * 64 + f] = o;
        }
    }
    if (tid < 192) {
        int row = tid / 3, comp = tid % 3;
        int n = gbase + row;
        if (n < N) {
            float s = ((const float*)&sXdP[row * 4 + 0])[comp]
                    + ((const float*)&sXdP[row * 4 + 1])[comp]
                    + ((const float*)&sXdP[row * 4 + 2])[comp]
                    + ((const float*)&sXdP[row * 4 + 3])[comp];
            xout[(size_t)n * 3 + comp] = x[(size_t)n * 3 + comp] + s;
        }
    }
}

// --- launch --------------------------------------------------------------

extern "C" void kernel_launch(void* const* d_in, const int* in_sizes, int n_in,
                              void* d_out, int out_size, void* d_ws, size_t ws_size,
                              hipStream_t stream) {
    const float* h    = (const float*)d_in[0];
    const float* x    = (const float*)d_in[1];
    const int*   edst = (const int*)d_in[2];
    const int*   esrc = (const int*)d_in[3];
    const float* means= (const float*)d_in[4];
    const float* stds = (const float*)d_in[5];
    const float* Wm1  = (const float*)d_in[6];
    const float* bm1  = (const float*)d_in[7];
    const float* Wm2  = (const float*)d_in[8];
    const float* bm2  = (const float*)d_in[9];
    const float* Wa   = (const float*)d_in[10];
    const float* ba   = (const float*)d_in[11];
    const float* Wx1  = (const float*)d_in[12];
    const float* bx1  = (const float*)d_in[13];
    const float* Wx2  = (const float*)d_in[14];
    const float* Wh1  = (const float*)d_in[15];
    const float* bh1  = (const float*)d_in[16];
    const float* Wh2  = (const float*)d_in[17];
    const float* bh2  = (const float*)d_in[18];

    const int N = in_sizes[0] / 64;
    const int E = in_sizes[2];
    const int nb = (N + 1023) / 1024;

    float* hout = (float*)d_out;
    float* xout = hout + (size_t)N * 64;

    // workspace layout
    uintptr_t wp = (uintptr_t)d_ws;
    int* counts = (int*)wp;                 wp += (size_t)N * 4;
    int* off    = (int*)wp;                 wp += (size_t)(N + 1) * 4;
    int* local  = (int*)wp;                 wp += (size_t)N * 4;
    int* bsum   = (int*)wp;                 wp += 1024 * 4;
    int* rankv  = (int*)wp;                 wp += (size_t)E * 4;
    wp = (wp + 255) & ~(uintptr_t)255;
    short* msg  = (short*)wp;               wp += (size_t)E * 64 * 2;
    wp = (wp + 255) & ~(uintptr_t)255;
    float* disp = (float*)wp;               wp += (size_t)E * 16;
    wp = (wp + 255) & ~(uintptr_t)255;
    short* hbf  = (short*)wp;               wp += (size_t)N * 64 * 2;
    wp = (wp + 255) & ~(uintptr_t)255;
    short* wfrag = (short*)wp;              wp += 4096 * 8 * 2;

    // CSR offsets + per-edge ranks (one atomic pass) + h->bf16 fused
    (void)hipMemsetAsync(counts, 0, (size_t)N * 4, stream);
    {
        int n4 = N * 16;                     // h elements / 4
        int range = (E > n4) ? E : n4;
        hist_h2bf_kernel<<<(range + 255) / 256, 256, 0, stream>>>(
            edst, counts, rankv, E, (const float4*)h, (uint2*)hbf, n4);
    }
    scan1_kernel<<<nb, 1024, 0, stream>>>(counts, local, bsum, N);
    scan2_kernel<<<1, 1024, 0, stream>>>(bsum, nb);
    scan3_kernel<<<(N + 255) / 256, 256, 0, stream>>>(local, bsum, off, N, E);
    wfrag_kernel<<<16, 256, 0, stream>>>(Wm1, Wm2, Wx1, Wh1, Wh2, wfrag);

    // edge pipeline
    const int ngroups = (E + 63) / 64;
    edge_kernel<<<1024, 256, 0, stream>>>(hbf, x, edst, esrc, off, rankv, means, stds,
                                          wfrag, bm1, bm2, Wa, ba, bx1, Wx2,
                                          msg, disp, E, ngroups);

    // node update
    node_kernel<<<(N + 63) / 64, 256, 0, stream>>>(hbf, h, x, off, msg, disp,
                                                   wfrag + 2560 * 8,
                                                   bh1, bh2, hout, xout, N);
}